// Round 9
// baseline (1696.301 us; speedup 1.0000x reference)
//
#include <hip/hip_runtime.h>

#define N_TOTAL 150000   // N_USERS + M_ITEMS
#define DIM 64
#define RPB 256          // rows per bucket (pow2)
#define NBUCK 586        // ceil(150000/256)
#define CAP 9024         // fixed bucket capacity (mean 8192 + 9.2 sigma)
#define CHUNK 16384      // edges per binning block (1024 thr x 16)

typedef float v2f __attribute__((ext_vector_type(2)));

__global__ void fill_bcur_kernel(int* __restrict__ bcur) {
    int t = blockIdx.x * 256 + threadIdx.x;
    if (t < NBUCK) bcur[t] = t * CAP;
}

// Phase B: LDS multisplit into NBUCK row-range buckets; packed 8B records,
// contiguous runs per (block,bucket) into fixed-capacity bucket regions.
// pk.x = rowLocal(8b)<<18 | col(18b) ; pk.y = f32 val bits
__global__ void bin_kernel(const int* __restrict__ idx, const float* __restrict__ val,
                           int* __restrict__ bcur, uint2* __restrict__ binned, int nnz) {
    __shared__ int lcnt[NBUCK];
    __shared__ int lbase[NBUCK];
    int t = threadIdx.x;
    int base = blockIdx.x * CHUNK;
    for (int b = t; b < NBUCK; b += 1024) lcnt[b] = 0;
    __syncthreads();
    int rows[16];
    #pragma unroll
    for (int i = 0; i < 16; ++i) {
        int e = base + t + i * 1024;
        int r = (e < nnz) ? idx[e] : -1;
        rows[i] = r;
        if (r >= 0) atomicAdd(&lcnt[r >> 8], 1);
    }
    __syncthreads();
    for (int b = t; b < NBUCK; b += 1024) {
        int c = lcnt[b];
        lbase[b] = c ? atomicAdd(&bcur[b], c) : 0;
        lcnt[b] = 0;     // reuse as intra-block offset
    }
    __syncthreads();
    #pragma unroll
    for (int i = 0; i < 16; ++i) {
        int r = rows[i];
        if (r >= 0) {
            int e = base + t + i * 1024;
            int b = r >> 8;
            int o = atomicAdd(&lcnt[b], 1);
            int pos = lbase[b] + o;
            if (pos < (b + 1) * CAP) {   // overflow guard (never hit at 9.2 sigma)
                uint2 pk;
                pk.x = ((unsigned)(r & 255) << 18) | (unsigned)idx[nnz + e];
                pk.y = __float_as_uint(val[e]);
                binned[pos] = pk;
            }
        }
    }
}

// Phase C: per-bucket exact CSR placement; packed 4B cs entries:
//   cs[k] = col(18b)<<14 | val14  (val14 = rounded f32 bits >> 18, sign+8e+5m)
__global__ void scatterc_kernel(const uint2* __restrict__ binned, const int* __restrict__ bcur,
                                int* __restrict__ rlo, int* __restrict__ rhi,
                                unsigned* __restrict__ cs) {
    __shared__ int hist[RPB];
    __shared__ int cur[RPB];
    int b = blockIdx.x;
    int s = b * CAP;
    int e = min(bcur[b], s + CAP);
    int t = threadIdx.x;
    hist[t] = 0;
    __syncthreads();
    for (int k = s + t; k < e; k += 256)
        atomicAdd(&hist[binned[k].x >> 18], 1);
    __syncthreads();
    int v = hist[t];
    cur[t] = v;
    __syncthreads();
    for (int off = 1; off < 256; off <<= 1) {
        int x = (t >= off) ? cur[t - off] : 0;
        __syncthreads();
        cur[t] += x;
        __syncthreads();
    }
    int rbase = s + cur[t] - v;
    int row = (b << 8) + t;
    if (row < N_TOTAL) { rlo[row] = rbase; rhi[row] = rbase + v; }
    cur[t] = rbase;
    __syncthreads();
    for (int k = s + t; k < e; k += 256) {
        uint2 ed = binned[k];
        int rl = ed.x >> 18;
        int o = atomicAdd(&cur[rl], 1);
        unsigned v14 = (ed.y + 0x20000u) >> 18;       // round-to-14-bit float
        cs[o] = ((ed.x & 0x3FFFFu) << 14) | v14;
    }
}

// ---- out = sum_f (w[f]/4) * emb_f (exact f32 layer-0 contribution) ----
__global__ void init_out_kernel(const float* __restrict__ e0, const float* __restrict__ e1,
                                const float* __restrict__ e2, const float* __restrict__ w,
                                float* __restrict__ out, int n4) {
    int i = blockIdx.x * blockDim.x + threadIdx.x;
    if (i >= n4) return;
    float c0 = w[0] * 0.25f, c1 = w[1] * 0.25f, c2 = w[2] * 0.25f;
    float4 a = reinterpret_cast<const float4*>(e0)[i];
    float4 b = reinterpret_cast<const float4*>(e1)[i];
    float4 c = reinterpret_cast<const float4*>(e2)[i];
    float4 o;
    o.x = c0 * a.x + c1 * b.x + c2 * c.x;
    o.y = c0 * a.y + c1 * b.y + c2 * c.y;
    o.z = c0 * a.z + c1 * b.z + c2 * c.z;
    o.w = c0 * a.w + c1 * b.w + c2 * c.w;
    reinterpret_cast<float4*>(out)[i] = o;
}

// f32 -> fp8(e4m3, x64 scale) conversion into dim-split half-tables.
// Thread i handles 8 consecutive dims: row = i>>3, g = i&7; g<4 -> lo, else hi.
__global__ void conv_fp8_kernel(const float* __restrict__ x, uint2* __restrict__ xlo,
                                uint2* __restrict__ xhi, int n8) {
    int i = blockIdx.x * blockDim.x + threadIdx.x;
    if (i >= n8) return;
    const float4* x4 = reinterpret_cast<const float4*>(x);
    float4 a = x4[2 * i], b = x4[2 * i + 1];
    int p0 = __builtin_amdgcn_cvt_pk_fp8_f32(a.x * 64.f, a.y * 64.f, 0, false);
    p0 = __builtin_amdgcn_cvt_pk_fp8_f32(a.z * 64.f, a.w * 64.f, p0, true);
    int p1 = __builtin_amdgcn_cvt_pk_fp8_f32(b.x * 64.f, b.y * 64.f, 0, false);
    p1 = __builtin_amdgcn_cvt_pk_fp8_f32(b.z * 64.f, b.w * 64.f, p1, true);
    uint2 o;
    o.x = (unsigned)p0;
    o.y = (unsigned)p1;
    int row = i >> 3, g = i & 7;
    uint2* dst = (g < 4) ? xlo : xhi;
    dst[row * 4 + (g & 3)] = o;
}

// ---- pull SpMM over ONE 32-dim half-table (4.8MB, ~L2-resident).
// One wave per row; eighth-wave (8 lanes x u32 = 4 fp8 dims) per edge:
// 8 edges concurrent x 2-deep pipeline = 16 edges in flight per wave.
// Epilogue: out[row][hs*32..] += (w[f]/4/64)*acc (f32), y-half = fp8(acc). ----
template <bool LAST>
__global__ void spmm_fp8_kernel(const int* __restrict__ rlo, const int* __restrict__ rhi,
                                const unsigned* __restrict__ cs, const unsigned* __restrict__ x,
                                unsigned* __restrict__ y, float* __restrict__ out,
                                const float* __restrict__ w, int f, int hs, int nrows) {
    int gid = blockIdx.x * blockDim.x + threadIdx.x;
    int row = gid >> 6;
    int lane = gid & 63;
    if (row >= nrows) return;
    int s = rlo[row], e = rhi[row];
    int q = lane >> 3, sub = lane & 7;
    float ac[2][4];
    #pragma unroll
    for (int j = 0; j < 2; ++j) {
        ac[j][0] = 0.f; ac[j][1] = 0.f; ac[j][2] = 0.f; ac[j][3] = 0.f;
    }
    int k = s + q;
    for (; k + 8 < e; k += 16) {
        unsigned ed0 = cs[k], ed1 = cs[k + 8];
        unsigned g0 = x[((size_t)(ed0 >> 14) << 3) + sub];
        unsigned g1 = x[((size_t)(ed1 >> 14) << 3) + sub];
        float v0 = __uint_as_float((ed0 & 0x3FFFu) << 18);
        float v1 = __uint_as_float((ed1 & 0x3FFFu) << 18);
        v2f lo0 = __builtin_amdgcn_cvt_pk_f32_fp8((int)g0, false);
        v2f hi0 = __builtin_amdgcn_cvt_pk_f32_fp8((int)g0, true);
        v2f lo1 = __builtin_amdgcn_cvt_pk_f32_fp8((int)g1, false);
        v2f hi1 = __builtin_amdgcn_cvt_pk_f32_fp8((int)g1, true);
        ac[0][0] += v0 * lo0.x; ac[0][1] += v0 * lo0.y;
        ac[0][2] += v0 * hi0.x; ac[0][3] += v0 * hi0.y;
        ac[1][0] += v1 * lo1.x; ac[1][1] += v1 * lo1.y;
        ac[1][2] += v1 * hi1.x; ac[1][3] += v1 * hi1.y;
    }
    for (; k < e; k += 8) {
        unsigned ed = cs[k];
        unsigned g = x[((size_t)(ed >> 14) << 3) + sub];
        float vv = __uint_as_float((ed & 0x3FFFu) << 18);
        v2f lo = __builtin_amdgcn_cvt_pk_f32_fp8((int)g, false);
        v2f hi = __builtin_amdgcn_cvt_pk_f32_fp8((int)g, true);
        ac[0][0] += vv * lo.x;
        ac[0][1] += vv * lo.y;
        ac[0][2] += vv * hi.x;
        ac[0][3] += vv * hi.y;
    }
    float a0 = ac[0][0] + ac[1][0];
    float a1 = ac[0][1] + ac[1][1];
    float a2 = ac[0][2] + ac[1][2];
    float a3 = ac[0][3] + ac[1][3];
    a0 += __shfl_xor(a0, 8); a0 += __shfl_xor(a0, 16); a0 += __shfl_xor(a0, 32);
    a1 += __shfl_xor(a1, 8); a1 += __shfl_xor(a1, 16); a1 += __shfl_xor(a1, 32);
    a2 += __shfl_xor(a2, 8); a2 += __shfl_xor(a2, 16); a2 += __shfl_xor(a2, 32);
    a3 += __shfl_xor(a3, 8); a3 += __shfl_xor(a3, 16); a3 += __shfl_xor(a3, 32);
    if (q == 0) {
        if (!LAST) {
            int p = __builtin_amdgcn_cvt_pk_fp8_f32(a0, a1, 0, false);
            p = __builtin_amdgcn_cvt_pk_fp8_f32(a2, a3, p, true);
            y[((size_t)row << 3) + sub] = (unsigned)p;
        }
        float c = w[f] * (0.25f / 64.f);
        float4* o4 = reinterpret_cast<float4*>(out) + (((size_t)row << 4) + (hs << 3) + sub);
        float4 cv = *o4;
        cv.x += c * a0;
        cv.y += c * a1;
        cv.z += c * a2;
        cv.w += c * a3;
        *o4 = cv;
    }
}

extern "C" void kernel_launch(void* const* d_in, const int* in_sizes, int n_in,
                              void* d_out, int out_size, void* d_ws, size_t ws_size,
                              hipStream_t stream) {
    const float* emb[3]  = {(const float*)d_in[0], (const float*)d_in[1], (const float*)d_in[2]};
    const int*   gidx[3] = {(const int*)d_in[3],   (const int*)d_in[5],   (const int*)d_in[7]};
    const float* gval[3] = {(const float*)d_in[4], (const float*)d_in[6], (const float*)d_in[8]};
    const float* w = (const float*)d_in[9];
    float* out = (float*)d_out;

    const int nnz = in_sizes[4];
    const size_t bufElems = (size_t)N_TOTAL * DIM;       // 9.6M
    const size_t halfBytes = bufElems / 2;               // 4.8 MB per half-table
    const size_t capElems = (size_t)NBUCK * CAP;         // 5.29M entries

    // ws layout:
    //   [0, 42.3MB)      binned (uint2) -- aliases the 6 fp8 half-tables (28.8MB)
    //   [42.3, 63.5MB)   cs (u32, bucket-strided)
    //   then rlo, rhi, bcur
    char* base = (char*)d_ws;
    uint2*    binned = (uint2*)base;
    unsigned* embLo = (unsigned*)(base + 0 * halfBytes);   // live after scatterc
    unsigned* embHi = (unsigned*)(base + 1 * halfBytes);
    unsigned* aLo   = (unsigned*)(base + 2 * halfBytes);   // live after spmm L1
    unsigned* aHi   = (unsigned*)(base + 3 * halfBytes);
    unsigned* bLo   = (unsigned*)(base + 4 * halfBytes);   // live after spmm L2
    unsigned* bHi   = (unsigned*)(base + 5 * halfBytes);
    unsigned* cs    = (unsigned*)(base + capElems * 8);
    int*      rlo   = (int*)(base + capElems * 8 + capElems * 4);
    int*      rhi   = rlo + N_TOTAL;
    int*      bcur  = rhi + N_TOTAL;

    const int n4 = (int)(bufElems / 4);
    const int n8 = (int)(bufElems / 8);
    dim3 eltGrid((n4 + 255) / 256);
    dim3 cvtGrid((n8 + 255) / 256);
    dim3 chunkGrid((nnz + CHUNK - 1) / CHUNK);            // 293
    dim3 rowGrid((unsigned)(((size_t)N_TOTAL * 64 + 255) / 256));

    // layer-0 contributions of all factors in one pass (exact f32)
    init_out_kernel<<<eltGrid, 256, 0, stream>>>(emb[0], emb[1], emb[2], w, out, n4);

    for (int f = 0; f < 3; ++f) {
        // --- bucket build (fixed-capacity: no global hist/scan needed) ---
        fill_bcur_kernel<<<3, 256, 0, stream>>>(bcur);
        bin_kernel<<<chunkGrid, 1024, 0, stream>>>(gidx[f], gval[f], bcur, binned, nnz);
        scatterc_kernel<<<NBUCK, 256, 0, stream>>>(binned, bcur, rlo, rhi, cs);

        // --- fp8 half-tables of this factor's embedding (binned dead now) ---
        conv_fp8_kernel<<<cvtGrid, 256, 0, stream>>>(emb[f], (uint2*)embLo, (uint2*)embHi, n8);

        // --- 3 propagation layers x 2 dim-halves, axpy fused into epilogue ---
        spmm_fp8_kernel<false><<<rowGrid, 256, 0, stream>>>(rlo, rhi, cs, embLo, aLo,
                                                            out, w, f, 0, N_TOTAL);
        spmm_fp8_kernel<false><<<rowGrid, 256, 0, stream>>>(rlo, rhi, cs, embHi, aHi,
                                                            out, w, f, 1, N_TOTAL);
        spmm_fp8_kernel<false><<<rowGrid, 256, 0, stream>>>(rlo, rhi, cs, aLo, bLo,
                                                            out, w, f, 0, N_TOTAL);
        spmm_fp8_kernel<false><<<rowGrid, 256, 0, stream>>>(rlo, rhi, cs, aHi, bHi,
                                                            out, w, f, 1, N_TOTAL);
        spmm_fp8_kernel<true><<<rowGrid, 256, 0, stream>>>(rlo, rhi, cs, bLo, nullptr,
                                                           out, w, f, 0, N_TOTAL);
        spmm_fp8_kernel<true><<<rowGrid, 256, 0, stream>>>(rlo, rhi, cs, bHi, nullptr,
                                                           out, w, f, 1, N_TOTAL);
    }
}

// Round 10
// 1154.614 us; speedup vs baseline: 1.4692x; 1.4692x over previous
//
#include <hip/hip_runtime.h>

#define N_TOTAL 150000   // N_USERS + M_ITEMS
#define DIM 64
#define RPB 256          // rows per bucket (pow2)
#define NBUCK 586        // ceil(150000/256)
#define CAP 9024         // fixed bucket capacity (mean 8192 + 9.2 sigma)
#define CHUNK 8192       // edges per binning block (512 thr x 16)

typedef float v2f __attribute__((ext_vector_type(2)));

__global__ void fill_bcur_kernel(int* __restrict__ bcur) {
    int t = blockIdx.x * 256 + threadIdx.x;
    if (t < NBUCK) bcur[t] = t * CAP;
}

// Phase B: LDS-sorted multisplit. Block stages its 8192 edges in LDS sorted by
// bucket, reserves per-bucket global runs, then streams LDS->global with
// consecutive threads writing consecutive addresses (full-line coalesced
// stores; ~1.1x write amp instead of 5.2M scattered 8B transactions).
// record: pk.x = rowLocal(8b)<<18 | col(18b) ; pk.y = f32 val bits
__global__ void bin_kernel(const int* __restrict__ idx, const float* __restrict__ val,
                           int* __restrict__ bcur, uint2* __restrict__ binned, int nnz) {
    __shared__ uint2 sedge[CHUNK];        // 64 KB
    __shared__ int lcnt[NBUCK];
    __shared__ int lstart[NBUCK + 1];
    __shared__ int gbase[NBUCK];
    __shared__ int ssc[512];
    int t = threadIdx.x;
    int base = blockIdx.x * CHUNK;
    int nEdges = min(CHUNK, nnz - base);
    for (int b = t; b < NBUCK; b += 512) lcnt[b] = 0;
    __syncthreads();
    uint2 myedge[16];
    int myb[16];
    #pragma unroll
    for (int i = 0; i < 16; ++i) {
        int e = base + t + i * 512;
        if (e < nnz) {
            int r = idx[e];
            myb[i] = r >> 8;
            myedge[i].x = ((unsigned)(r & 255) << 18) | (unsigned)idx[nnz + e];
            myedge[i].y = __float_as_uint(val[e]);
            atomicAdd(&lcnt[r >> 8], 1);
        } else {
            myb[i] = -1;
        }
    }
    __syncthreads();
    // exclusive scan of lcnt (2 elements per thread, blocked) -> lstart
    int i0 = 2 * t;
    int c0 = (i0 < NBUCK) ? lcnt[i0] : 0;
    int c1 = (i0 + 1 < NBUCK) ? lcnt[i0 + 1] : 0;
    int s2 = c0 + c1;
    ssc[t] = s2;
    __syncthreads();
    for (int off = 1; off < 512; off <<= 1) {
        int x = (t >= off) ? ssc[t - off] : 0;
        __syncthreads();
        ssc[t] += x;
        __syncthreads();
    }
    int excl = ssc[t] - s2;
    if (i0 <= NBUCK) lstart[i0] = excl;
    if (i0 + 1 <= NBUCK) lstart[i0 + 1] = excl + c0;
    // reserve global runs; reset lcnt as placement cursors
    for (int b = t; b < NBUCK; b += 512) {
        int c = lcnt[b];
        gbase[b] = c ? atomicAdd(&bcur[b], c) : 0;
        lcnt[b] = 0;
    }
    __syncthreads();
    // place into LDS in bucket-sorted order
    #pragma unroll
    for (int i = 0; i < 16; ++i) {
        int b = myb[i];
        if (b >= 0) {
            int o = atomicAdd(&lcnt[b], 1);
            sedge[lstart[b] + o] = myedge[i];
        }
    }
    __syncthreads();
    // stream out coalesced; bucket of position p via binary search on lstart
    for (int p = t; p < nEdges; p += 512) {
        int lo = 0, hi = NBUCK;
        while (hi - lo > 1) {
            int mid = (lo + hi) >> 1;
            if (lstart[mid] <= p) lo = mid; else hi = mid;
        }
        int dst = gbase[lo] + (p - lstart[lo]);
        if (dst < (lo + 1) * CAP)   // overflow guard (never hit at 9.2 sigma)
            binned[dst] = sedge[p];
    }
}

// Phase C: per-bucket exact CSR placement; packed 4B cs entries:
//   cs[k] = col(18b)<<14 | val14  (val14 = rounded f32 bits >> 18, sign+8e+5m)
__global__ void scatterc_kernel(const uint2* __restrict__ binned, const int* __restrict__ bcur,
                                int* __restrict__ rlo, int* __restrict__ rhi,
                                unsigned* __restrict__ cs) {
    __shared__ int hist[RPB];
    __shared__ int cur[RPB];
    int b = blockIdx.x;
    int s = b * CAP;
    int e = min(bcur[b], s + CAP);
    int t = threadIdx.x;
    hist[t] = 0;
    __syncthreads();
    for (int k = s + t; k < e; k += 256)
        atomicAdd(&hist[binned[k].x >> 18], 1);
    __syncthreads();
    int v = hist[t];
    cur[t] = v;
    __syncthreads();
    for (int off = 1; off < 256; off <<= 1) {
        int x = (t >= off) ? cur[t - off] : 0;
        __syncthreads();
        cur[t] += x;
        __syncthreads();
    }
    int rbase = s + cur[t] - v;
    int row = (b << 8) + t;
    if (row < N_TOTAL) { rlo[row] = rbase; rhi[row] = rbase + v; }
    cur[t] = rbase;
    __syncthreads();
    for (int k = s + t; k < e; k += 256) {
        uint2 ed = binned[k];
        int rl = ed.x >> 18;
        int o = atomicAdd(&cur[rl], 1);
        unsigned v14 = (ed.y + 0x20000u) >> 18;       // round-to-14-bit float
        cs[o] = ((ed.x & 0x3FFFFu) << 14) | v14;
    }
}

// ---- out = sum_f (w[f]/4) * emb_f (exact f32 layer-0 contribution) ----
__global__ void init_out_kernel(const float* __restrict__ e0, const float* __restrict__ e1,
                                const float* __restrict__ e2, const float* __restrict__ w,
                                float* __restrict__ out, int n4) {
    int i = blockIdx.x * blockDim.x + threadIdx.x;
    if (i >= n4) return;
    float c0 = w[0] * 0.25f, c1 = w[1] * 0.25f, c2 = w[2] * 0.25f;
    float4 a = reinterpret_cast<const float4*>(e0)[i];
    float4 b = reinterpret_cast<const float4*>(e1)[i];
    float4 c = reinterpret_cast<const float4*>(e2)[i];
    float4 o;
    o.x = c0 * a.x + c1 * b.x + c2 * c.x;
    o.y = c0 * a.y + c1 * b.y + c2 * c.y;
    o.z = c0 * a.z + c1 * b.z + c2 * c.z;
    o.w = c0 * a.w + c1 * b.w + c2 * c.w;
    reinterpret_cast<float4*>(out)[i] = o;
}

// f32 -> fp8(e4m3, x64 scale) table conversion. 8 dims per thread.
__global__ void conv_fp8_kernel(const float* __restrict__ x, uint2* __restrict__ y, int n8) {
    int i = blockIdx.x * blockDim.x + threadIdx.x;
    if (i >= n8) return;
    const float4* x4 = reinterpret_cast<const float4*>(x);
    float4 a = x4[2 * i], b = x4[2 * i + 1];
    int p0 = __builtin_amdgcn_cvt_pk_fp8_f32(a.x * 64.f, a.y * 64.f, 0, false);
    p0 = __builtin_amdgcn_cvt_pk_fp8_f32(a.z * 64.f, a.w * 64.f, p0, true);
    int p1 = __builtin_amdgcn_cvt_pk_fp8_f32(b.x * 64.f, b.y * 64.f, 0, false);
    p1 = __builtin_amdgcn_cvt_pk_fp8_f32(b.z * 64.f, b.w * 64.f, p1, true);
    uint2 o;
    o.x = (unsigned)p0;
    o.y = (unsigned)p1;
    y[i] = o;
}

// ---- pull SpMM, fp8 gather table (values are 64x true scale).
// One wave per row; quarter-wave (16 lanes x u32 = 4 fp8 dims) per edge,
// 4 edges concurrent + 4-deep pipeline = 16 edges in flight per wave.
// Epilogue: out[row] += (w[f]/4/64)*acc (f32 exact), y[row] = fp8(acc). ----
template <bool LAST>
__global__ void spmm_fp8_kernel(const int* __restrict__ rlo, const int* __restrict__ rhi,
                                const unsigned* __restrict__ cs, const unsigned* __restrict__ x,
                                unsigned* __restrict__ y, float* __restrict__ out,
                                const float* __restrict__ w, int f, int nrows) {
    int gid = blockIdx.x * blockDim.x + threadIdx.x;
    int row = gid >> 6;
    int lane = gid & 63;
    if (row >= nrows) return;
    int s = rlo[row], e = rhi[row];
    int q = lane >> 4, sub = lane & 15;
    float ac[4][4];
    #pragma unroll
    for (int j = 0; j < 4; ++j) {
        ac[j][0] = 0.f; ac[j][1] = 0.f; ac[j][2] = 0.f; ac[j][3] = 0.f;
    }
    int k = s + q;
    for (; k + 12 < e; k += 16) {
        unsigned ed[4], g[4];
        #pragma unroll
        for (int j = 0; j < 4; ++j) ed[j] = cs[k + 4 * j];
        #pragma unroll
        for (int j = 0; j < 4; ++j) g[j] = x[((size_t)(ed[j] >> 14) << 4) + sub];
        #pragma unroll
        for (int j = 0; j < 4; ++j) {
            float vv = __uint_as_float((ed[j] & 0x3FFFu) << 18);
            v2f lo = __builtin_amdgcn_cvt_pk_f32_fp8((int)g[j], false);
            v2f hi = __builtin_amdgcn_cvt_pk_f32_fp8((int)g[j], true);
            ac[j][0] += vv * lo.x;
            ac[j][1] += vv * lo.y;
            ac[j][2] += vv * hi.x;
            ac[j][3] += vv * hi.y;
        }
    }
    for (; k < e; k += 4) {
        unsigned ed = cs[k];
        unsigned g = x[((size_t)(ed >> 14) << 4) + sub];
        float vv = __uint_as_float((ed & 0x3FFFu) << 18);
        v2f lo = __builtin_amdgcn_cvt_pk_f32_fp8((int)g, false);
        v2f hi = __builtin_amdgcn_cvt_pk_f32_fp8((int)g, true);
        ac[0][0] += vv * lo.x;
        ac[0][1] += vv * lo.y;
        ac[0][2] += vv * hi.x;
        ac[0][3] += vv * hi.y;
    }
    float a0 = (ac[0][0] + ac[1][0]) + (ac[2][0] + ac[3][0]);
    float a1 = (ac[0][1] + ac[1][1]) + (ac[2][1] + ac[3][1]);
    float a2 = (ac[0][2] + ac[1][2]) + (ac[2][2] + ac[3][2]);
    float a3 = (ac[0][3] + ac[1][3]) + (ac[2][3] + ac[3][3]);
    a0 += __shfl_xor(a0, 16); a0 += __shfl_xor(a0, 32);
    a1 += __shfl_xor(a1, 16); a1 += __shfl_xor(a1, 32);
    a2 += __shfl_xor(a2, 16); a2 += __shfl_xor(a2, 32);
    a3 += __shfl_xor(a3, 16); a3 += __shfl_xor(a3, 32);
    if (q == 0) {
        if (!LAST) {
            int p = __builtin_amdgcn_cvt_pk_fp8_f32(a0, a1, 0, false);
            p = __builtin_amdgcn_cvt_pk_fp8_f32(a2, a3, p, true);
            y[((size_t)row << 4) + sub] = (unsigned)p;
        }
        float c = w[f] * (0.25f / 64.f);
        float4* o4 = reinterpret_cast<float4*>(out) + (((size_t)row << 4) + sub);
        float4 cv = *o4;
        cv.x += c * a0;
        cv.y += c * a1;
        cv.z += c * a2;
        cv.w += c * a3;
        *o4 = cv;
    }
}

extern "C" void kernel_launch(void* const* d_in, const int* in_sizes, int n_in,
                              void* d_out, int out_size, void* d_ws, size_t ws_size,
                              hipStream_t stream) {
    const float* emb[3]  = {(const float*)d_in[0], (const float*)d_in[1], (const float*)d_in[2]};
    const int*   gidx[3] = {(const int*)d_in[3],   (const int*)d_in[5],   (const int*)d_in[7]};
    const float* gval[3] = {(const float*)d_in[4], (const float*)d_in[6], (const float*)d_in[8]};
    const float* w = (const float*)d_in[9];
    float* out = (float*)d_out;

    const int nnz = in_sizes[4];
    const size_t bufElems = (size_t)N_TOTAL * DIM;       // 9.6M
    const size_t fp8Bytes = bufElems;                    // 9.6 MB per table
    const size_t capElems = (size_t)NBUCK * CAP;         // 5.29M entries

    // ws layout:
    //   [0, 42.3MB)      binned (uint2) -- aliases {emb8, bufA8, bufB8} (28.8MB)
    //   [42.3, 63.5MB)   cs (u32, bucket-strided)
    //   then rlo, rhi, bcur
    char* base = (char*)d_ws;
    uint2*    binned = (uint2*)base;
    unsigned* emb8   = (unsigned*)base;                       // live after scatterc
    unsigned* bufA8  = (unsigned*)(base + fp8Bytes);          // live after spmm L1
    unsigned* bufB8  = (unsigned*)(base + 2 * fp8Bytes);      // live after spmm L2
    unsigned* cs     = (unsigned*)(base + capElems * 8);
    int*      rlo    = (int*)(base + capElems * 8 + capElems * 4);
    int*      rhi    = rlo + N_TOTAL;
    int*      bcur   = rhi + N_TOTAL;

    const int n4 = (int)(bufElems / 4);
    const int n8 = (int)(bufElems / 8);
    dim3 eltGrid((n4 + 255) / 256);
    dim3 cvtGrid((n8 + 255) / 256);
    dim3 chunkGrid((nnz + CHUNK - 1) / CHUNK);            // 586
    dim3 rowGrid((unsigned)(((size_t)N_TOTAL * 64 + 255) / 256));

    // layer-0 contributions of all factors in one pass (exact f32)
    init_out_kernel<<<eltGrid, 256, 0, stream>>>(emb[0], emb[1], emb[2], w, out, n4);

    for (int f = 0; f < 3; ++f) {
        // --- bucket build (fixed-capacity: no global hist/scan needed) ---
        fill_bcur_kernel<<<3, 256, 0, stream>>>(bcur);
        bin_kernel<<<chunkGrid, 512, 0, stream>>>(gidx[f], gval[f], bcur, binned, nnz);
        scatterc_kernel<<<NBUCK, 256, 0, stream>>>(binned, bcur, rlo, rhi, cs);

        // --- fp8 copy of this factor's embedding (binned is dead now) ---
        conv_fp8_kernel<<<cvtGrid, 256, 0, stream>>>(emb[f], (uint2*)emb8, n8);

        // --- 3 propagation layers, axpy fused into SpMM epilogue ---
        spmm_fp8_kernel<false><<<rowGrid, 256, 0, stream>>>(rlo, rhi, cs, emb8, bufA8,
                                                            out, w, f, N_TOTAL);
        spmm_fp8_kernel<false><<<rowGrid, 256, 0, stream>>>(rlo, rhi, cs, bufA8, bufB8,
                                                            out, w, f, N_TOTAL);
        spmm_fp8_kernel<true><<<rowGrid, 256, 0, stream>>>(rlo, rhi, cs, bufB8, nullptr,
                                                           out, w, f, N_TOTAL);
    }
}